// Round 8
// baseline (66.025 us; speedup 1.0000x reference)
//
#include <hip/hip_runtime.h>
#include <math.h>

#define C_IN 2048
#define N_EXP 64
#define TPB 32            // tokens per block
#define NCH 64            // K chunks of 32
#define DELTA  3e-4f      // risky-gap threshold (>=100x expected logit error)
#define DELTA2 1e-3f      // candidate window around v2

typedef __bf16 bf16x8 __attribute__((ext_vector_type(8)));
typedef float f32x4 __attribute__((ext_vector_type(4)));

__device__ __forceinline__ void cvt_split(float f, ushort& h, ushort& l) {
    uint u = __float_as_uint(f);
    uint hr = (u + (0x7FFFu + ((u >> 16) & 1u))) >> 16;
    h = (ushort)hr;
    float hf = __uint_as_float(hr << 16);
    uint v = __float_as_uint(f - hf);
    l = (ushort)((v + (0x7FFFu + ((v >> 16) & 1u))) >> 16);
}

// W [64][2048] fp32 -> CHUNK-MAJOR bf16 hi/lo: o = (k>>5)*2048 + e*32 + (k&31).
// One K-chunk (32 cols x 64 experts) = 4 KB contiguous -> the main kernel's
// gload_lds staging of a chunk is one fully-sequential 4 KB block read.
__global__ void conv_w_kernel(const float* __restrict__ W,
                              ushort* __restrict__ whc, ushort* __restrict__ wlc) {
    const int i = blockIdx.x * 256 + threadIdx.x;   // e*2048 + k
    const int e = i >> 11, k = i & 2047;
    const int o = (k >> 5) * 2048 + e * 32 + (k & 31);
    ushort h, lo;
    cvt_split(W[i], h, lo);
    whc[o] = h;
    wlc[o] = lo;
}

__device__ __forceinline__ void glds16(const ushort* g, ushort* l) {
    __builtin_amdgcn_global_load_lds(
        (const __attribute__((address_space(1))) uint32_t*)g,
        (__attribute__((address_space(3))) uint32_t*)l, 16, 0, 0);
}

#define VMW(N) do { asm volatile("s_waitcnt vmcnt(" #N ")" ::: "memory");     \
                    __builtin_amdgcn_sched_barrier(0); } while (0)

// cvt a float4 of x into bf16 hi/lo and ds_write into x slot S2
#define CVTW(XV, S2) do {                                                     \
    ushort h0_, h1_, h2_, h3_, q0_, q1_, q2_, q3_;                            \
    cvt_split((XV).x, h0_, q0_); cvt_split((XV).y, h1_, q1_);                 \
    cvt_split((XV).z, h2_, q2_); cvt_split((XV).w, h3_, q3_);                 \
    uint2 hv_ = {(uint)h0_ | ((uint)h1_ << 16), (uint)h2_ | ((uint)h3_ << 16)}; \
    uint2 lv_ = {(uint)q0_ | ((uint)q1_ << 16), (uint)q2_ | ((uint)q3_ << 16)}; \
    *(uint2*)&smem[16384 + (S2) * 2048 + xw] = hv_;                           \
    *(uint2*)&smem[16384 + (S2) * 2048 + 1024 + xw] = lv_;                    \
} while (0)

// One K-step. u: LDS slot (compile-time), W1: chunk-landed vmcnt, STG: stage
// chunk cc+u+4, CVT: convert+write chunk cc+u+2 after vmcnt(W2).
#define KSTEP(u, W1, STG, CVT, W2) do {                                       \
    VMW(W1);                                                                  \
    __builtin_amdgcn_s_barrier();                                             \
    const ushort* xs_ = smem + 16384 + (u) * 2048;                            \
    const ushort* ws_ = smem + (u) * 4096;                                    \
    uint4 rah0 = *(const uint4*)&xs_[aoff];                                   \
    uint4 rah1 = *(const uint4*)&xs_[512 + aoff];                             \
    uint4 ral0 = *(const uint4*)&xs_[1024 + aoff];                            \
    uint4 ral1 = *(const uint4*)&xs_[1536 + aoff];                            \
    uint4 rbh  = *(const uint4*)&ws_[boff];                                   \
    uint4 rbl  = *(const uint4*)&ws_[2048 + boff];                            \
    asm volatile("s_waitcnt lgkmcnt(0)" ::: "memory");                        \
    __builtin_amdgcn_sched_barrier(0);                                        \
    __builtin_amdgcn_s_barrier();                                             \
    if (STG) {                                                                \
        const int c4_ = cc + (u) + 4;                                         \
        glds16(whc + (size_t)c4_ * 2048 + tid * 8,                            \
               smem + (u) * 4096 + wavebase);                                 \
        glds16(wlc + (size_t)c4_ * 2048 + tid * 8,                            \
               smem + (u) * 4096 + 2048 + wavebase);                          \
        xr[u] = *(const float4*)(xg + (size_t)xrow * C_IN + c4_ * 32 + xq * 4); \
        __builtin_amdgcn_sched_barrier(0);                                    \
    }                                                                         \
    __builtin_amdgcn_s_setprio(1);                                            \
    {                                                                         \
        bf16x8 ah0 = __builtin_bit_cast(bf16x8, rah0);                        \
        bf16x8 ah1 = __builtin_bit_cast(bf16x8, rah1);                        \
        bf16x8 al0 = __builtin_bit_cast(bf16x8, ral0);                        \
        bf16x8 al1 = __builtin_bit_cast(bf16x8, ral1);                        \
        bf16x8 bh = __builtin_bit_cast(bf16x8, rbh);                          \
        bf16x8 bl = __builtin_bit_cast(bf16x8, rbl);                          \
        acc0 = __builtin_amdgcn_mfma_f32_16x16x32_bf16(ah0, bh, acc0, 0, 0, 0); \
        acc1 = __builtin_amdgcn_mfma_f32_16x16x32_bf16(ah1, bh, acc1, 0, 0, 0); \
        acc0 = __builtin_amdgcn_mfma_f32_16x16x32_bf16(al0, bh, acc0, 0, 0, 0); \
        acc1 = __builtin_amdgcn_mfma_f32_16x16x32_bf16(al1, bh, acc1, 0, 0, 0); \
        acc0 = __builtin_amdgcn_mfma_f32_16x16x32_bf16(ah0, bl, acc0, 0, 0, 0); \
        acc1 = __builtin_amdgcn_mfma_f32_16x16x32_bf16(ah1, bl, acc1, 0, 0, 0); \
    }                                                                         \
    __builtin_amdgcn_s_setprio(0);                                            \
    if (CVT) {                                                                \
        VMW(W2);                                                              \
        CVTW(xr[((u) + 2) & 3], ((u) + 2) & 3);                               \
    }                                                                         \
} while (0)

// Main: 512 blocks x 256 thr (4 waves) = 2 blocks/CU, 48 KB LDS.
// Wave w: 32 tokens x experts [w*16, w*16+16) x FULL K (no K-split).
// 4-deep chunk pipeline: W hi/lo via gload_lds (chunk-major, contiguous),
// x via reg->cvt->bf16 LDS (T14 issue-early/write-late). Counted vmcnt(9)/(6)
// per kstep — never drained mid-loop; raw s_barrier (no compiler drain).
// ~75 KB/CU of loads in flight. Epilogue: partials (pitch 65) + softmax/top-2
// + exact-fp32 repair (verified r3-r7 epilogue).
__global__ __launch_bounds__(256, 2) void topk_gate_kernel(
    const float* __restrict__ x, const float* __restrict__ Wf,
    const float* __restrict__ b, const ushort* __restrict__ whc,
    const ushort* __restrict__ wlc, float* __restrict__ out)
{
    // [0..16383]   W slots 0..3: per slot 4096 ushorts = hi[64][32] + lo[64][32]
    // [16384..24575] x slots 0..3: per slot 2048 ushorts = hi[32][32] + lo[32][32]
    __shared__ __align__(16) ushort smem[24576];   // 48 KB

    const int tid = threadIdx.x;
    const int w = tid >> 6, l = tid & 63;
    const int tr = l & 15, kg = l >> 4;
    const int xrow = tid >> 3, xq = tid & 7;
    const int t0 = blockIdx.x * TPB;
    const int wavebase = w * 512;                 // gload_lds wave-uniform dest
    const int aoff = tr * 32 + kg * 8;            // A-frag read (ushorts)
    const int boff = (w * 16 + tr) * 32 + kg * 8; // B-frag read (ushorts)
    const int xw = xrow * 32 + xq * 4;            // x cvt-write (ushorts)

    const float* xg = x + (size_t)t0 * C_IN;

    f32x4 acc0 = {0.f, 0.f, 0.f, 0.f};
    f32x4 acc1 = {0.f, 0.f, 0.f, 0.f};
    float4 xr[4];   // all indices compile-time (unroll-4) -> stays in VGPRs

    // ---- prologue: issue chunks 0..3 (order per chunk: Whi, Wlo, x) ----
#pragma unroll
    for (int c0 = 0; c0 < 4; ++c0) {
        glds16(whc + (size_t)c0 * 2048 + tid * 8, smem + c0 * 4096 + wavebase);
        glds16(wlc + (size_t)c0 * 2048 + tid * 8, smem + c0 * 4096 + 2048 + wavebase);
        xr[c0] = *(const float4*)(xg + (size_t)xrow * C_IN + c0 * 32 + xq * 4);
        __builtin_amdgcn_sched_barrier(0);
    }
    VMW(6);            // chunks 0,1 fully landed (2,3 still in flight)
    CVTW(xr[0], 0);
    CVTW(xr[1], 1);
    asm volatile("s_waitcnt lgkmcnt(0)" ::: "memory");
    __builtin_amdgcn_sched_barrier(0);

    int cc = 0;
#pragma unroll 1
    for (int j = 0; j < 15; ++j) {   // chunks 0..59
        KSTEP(0, 9, 1, 1, 6);
        KSTEP(1, 9, 1, 1, 6);
        KSTEP(2, 9, 1, 1, 6);
        KSTEP(3, 9, 1, 1, 6);
        cc += 4;
    }
    // tail: chunks 60..63 (no staging; counts shrink as queue drains)
    KSTEP(0, 9, 0, 1, 3);
    KSTEP(1, 6, 0, 1, 0);
    KSTEP(2, 3, 0, 0, 0);
    KSTEP(3, 0, 0, 0, 0);

    // ---- partials (pitch 65 vs bank aliasing), then the one full sync ----
    float* part = (float*)smem;   // [32][65] fp32 = 8.3 KB (over W slots 0/1)
#pragma unroll
    for (int r = 0; r < 4; ++r) {
        part[(kg * 4 + r) * 65 + w * 16 + tr] = acc0[r];
        part[(16 + kg * 4 + r) * 65 + w * 16 + tr] = acc1[r];
    }
    __syncthreads();

    // ---- softmax + top-2 + exact-fp32 repair (wave w: tokens w*8..w*8+7) ----
    const int e = l;
    const float be = b[e];
    for (int ti = 0; ti < 8; ++ti) {
        const int t = w * 8 + ti;
        float logit = part[t * 65 + e] + be;

        float v1, v2, v3; int i1, i2;
        for (int pass = 0; pass < 2; ++pass) {
            v1 = logit; i1 = e;
#pragma unroll
            for (int off = 32; off >= 1; off >>= 1) {
                float ov = __shfl_xor(v1, off, 64);
                int   oi = __shfl_xor(i1, off, 64);
                if (ov > v1 || (ov == v1 && oi < i1)) { v1 = ov; i1 = oi; }
            }
            v2 = (e == i1) ? -3.4e38f : logit;
            i2 = (e == i1) ? N_EXP : e;
#pragma unroll
            for (int off = 32; off >= 1; off >>= 1) {
                float ov = __shfl_xor(v2, off, 64);
                int   oi = __shfl_xor(i2, off, 64);
                if (ov > v2 || (ov == v2 && oi < i2)) { v2 = ov; i2 = oi; }
            }
            v3 = (e == i1 || e == i2) ? -3.4e38f : logit;
#pragma unroll
            for (int off = 32; off >= 1; off >>= 1) {
                float ov = __shfl_xor(v3, off, 64);
                v3 = (ov > v3) ? ov : v3;
            }
            if (pass == 1) break;
            const bool risky = (v1 - v2 < DELTA) || (v2 - v3 < DELTA);
            if (!risky) break;
            // exact fp32 recompute of candidate experts (wave-uniform path)
            unsigned long long cm = __ballot(logit >= v2 - DELTA2);
            const float* xrp = x + (size_t)(t0 + t) * C_IN;
            while (cm) {
                const int ce = __ffsll((unsigned long long)cm) - 1;
                cm &= cm - 1;
                const float* wr = Wf + (size_t)ce * C_IN;
                float p = 0.f;
#pragma unroll 8
                for (int i = 0; i < 32; ++i)
                    p = fmaf(xrp[l + 64 * i], wr[l + 64 * i], p);
#pragma unroll
                for (int off = 32; off >= 1; off >>= 1)
                    p += __shfl_xor(p, off, 64);
                if (e == ce) logit = p + be;
            }
        }

        float ex = expf(logit - v1);
        float ssum = ex;
#pragma unroll
        for (int off = 32; off >= 1; off >>= 1)
            ssum += __shfl_xor(ssum, off, 64);
        const float inv = 1.0f / ssum;
        const float p1 = inv;
        const float p2 = expf(v2 - v1) * inv;
        const float o = (e == i1) ? p1 : ((e == i2) ? p2 : 0.0f);
        out[(size_t)(t0 + t) * N_EXP + e] = o;
    }
}

extern "C" void kernel_launch(void* const* d_in, const int* in_sizes, int n_in,
                              void* d_out, int out_size, void* d_ws, size_t ws_size,
                              hipStream_t stream) {
    const float* x = (const float*)d_in[0];   // [4,4096,2048]
    const float* W = (const float*)d_in[1];   // [64,2048]
    const float* b = (const float*)d_in[2];   // [64]
    float* out = (float*)d_out;               // [4,4096,64]

    ushort* whc = (ushort*)d_ws;              // chunk-major bf16 hi, 256 KB
    ushort* wlc = whc + N_EXP * C_IN;         // chunk-major bf16 lo, 256 KB

    conv_w_kernel<<<512, 256, 0, stream>>>(W, whc, wlc);

    const int tokens = in_sizes[0] / C_IN;    // 16384
    const int grid = tokens / TPB;            // 512
    topk_gate_kernel<<<grid, 256, 0, stream>>>(x, W, b, whc, wlc, out);
}

// Round 9
// 58.836 us; speedup vs baseline: 1.1222x; 1.1222x over previous
//
#include <hip/hip_runtime.h>
#include <math.h>

#define C_IN 2048
#define N_EXP 64
#define TPB 16            // tokens per block (shared by all 4 waves)
#define KWIN 512          // per-wave K window (in-block K-split by 4)
#define KSTEPS 16         // KWIN / 32
#define DELTA  3e-4f      // risky-gap threshold (>=100x expected logit error)
#define DELTA2 1e-3f      // candidate window around v2

typedef __bf16 bf16x8 __attribute__((ext_vector_type(8)));
typedef float f32x4 __attribute__((ext_vector_type(4)));

__device__ __forceinline__ void cvt_split(float f, ushort& h, ushort& l) {
    uint u = __float_as_uint(f);
    uint hr = (u + (0x7FFFu + ((u >> 16) & 1u))) >> 16;
    h = (ushort)hr;
    float hf = __uint_as_float(hr << 16);
    uint v = __float_as_uint(f - hf);
    l = (ushort)((v + (0x7FFFu + ((v >> 16) & 1u))) >> 16);
}

// W [64][2048] fp32 -> frag-major bf16 hi/lo (256 KB each):
// o = (eg*64 + ks)*512 + lane*8 + j  <->  e = eg*16+(lane&15), k = ks*32+(lane>>4)*8+j
__global__ void conv_w_kernel(const float* __restrict__ W,
                              ushort* __restrict__ whf, ushort* __restrict__ wlf) {
    const int o = blockIdx.x * 256 + threadIdx.x;   // 0..131071
    const int egks = o >> 9;
    const int lane = (o >> 3) & 63;
    const int j = o & 7;
    const int e = (egks >> 6) * 16 + (lane & 15);
    const int k = (egks & 63) * 32 + (lane >> 4) * 8 + j;
    ushort h, lo;
    cvt_split(W[e * C_IN + k], h, lo);
    whf[o] = h;
    wlf[o] = lo;
}

// Main: identical to round-6 kernel (1024 blocks x 4 waves, 16 waves/CU,
// A-frags direct from global, W frag-major from L2, zero hot-loop barriers)
// EXCEPT one change: per-block K-phase rotation. Block bb's waves walk their
// 16 ksteps in order (ks + bb) & 15 instead of 0..15, applied consistently
// to both x and W addressing. This breaks the GPU-wide lockstep column sweep
// (all blocks reading the same 128B column window of 8KB-strided rows at the
// same instant -> HBM channel hotspotting at ~0.8 TB/s). A/B test: only this
// variable changed vs round 6.
__global__ __launch_bounds__(256, 4) void topk_gate_kernel(
    const float* __restrict__ x, const float* __restrict__ Wf,
    const float* __restrict__ b, const ushort* __restrict__ whf,
    const ushort* __restrict__ wlf, float* __restrict__ out)
{
    __shared__ float part[4][TPB][65];   // 16.25 KB; stride 65 spreads banks

    const int tid = threadIdx.x;
    const int wv = tid >> 6, l = tid & 63;
    const int t0 = blockIdx.x * TPB;
    const int tr = l & 15;        // token row within A-frag
    const int kg = l >> 4;        // k-group 0..3
    const int phase = blockIdx.x & 15;   // de-lockstep rotation

    const float* xg = x + (size_t)(t0 + tr) * C_IN + wv * KWIN + kg * 8;

    f32x4 acc[4];
#pragma unroll
    for (int eg = 0; eg < 4; ++eg) acc[eg] = (f32x4){0.f, 0.f, 0.f, 0.f};

#pragma unroll 2
    for (int ks = 0; ks < KSTEPS; ++ks) {
        const int kr = (ks + phase) & 15;   // rotated kstep (same set, new order)
        // A-fragment direct from global (fp32): 8 consecutive floats/lane
        const float4 a0 = *(const float4*)(xg + kr * 32);
        const float4 a1 = *(const float4*)(xg + kr * 32 + 4);
        // W-fragments, frag-major (contiguous per wave)
        const int ksa = wv * KSTEPS + kr;
        uint4 wb[8];
#pragma unroll
        for (int eg = 0; eg < 4; ++eg) {
            wb[eg * 2 + 0] = *(const uint4*)&whf[(eg * 64 + ksa) * 512 + l * 8];
            wb[eg * 2 + 1] = *(const uint4*)&wlf[(eg * 64 + ksa) * 512 + l * 8];
        }
        // split-convert A
        ushort h[8], q[8];
        cvt_split(a0.x, h[0], q[0]); cvt_split(a0.y, h[1], q[1]);
        cvt_split(a0.z, h[2], q[2]); cvt_split(a0.w, h[3], q[3]);
        cvt_split(a1.x, h[4], q[4]); cvt_split(a1.y, h[5], q[5]);
        cvt_split(a1.z, h[6], q[6]); cvt_split(a1.w, h[7], q[7]);
        uint4 hv = {(uint)h[0] | ((uint)h[1] << 16), (uint)h[2] | ((uint)h[3] << 16),
                    (uint)h[4] | ((uint)h[5] << 16), (uint)h[6] | ((uint)h[7] << 16)};
        uint4 qv = {(uint)q[0] | ((uint)q[1] << 16), (uint)q[2] | ((uint)q[3] << 16),
                    (uint)q[4] | ((uint)q[5] << 16), (uint)q[6] | ((uint)q[7] << 16)};
        bf16x8 ah = __builtin_bit_cast(bf16x8, hv);
        bf16x8 al = __builtin_bit_cast(bf16x8, qv);
#pragma unroll
        for (int eg = 0; eg < 4; ++eg) {
            bf16x8 bh = __builtin_bit_cast(bf16x8, wb[eg * 2 + 0]);
            bf16x8 bl = __builtin_bit_cast(bf16x8, wb[eg * 2 + 1]);
            acc[eg] = __builtin_amdgcn_mfma_f32_16x16x32_bf16(ah, bh, acc[eg], 0, 0, 0);
            acc[eg] = __builtin_amdgcn_mfma_f32_16x16x32_bf16(al, bh, acc[eg], 0, 0, 0);
            acc[eg] = __builtin_amdgcn_mfma_f32_16x16x32_bf16(ah, bl, acc[eg], 0, 0, 0);
        }
    }

    // ---- partials to LDS; the ONLY barrier ----
#pragma unroll
    for (int eg = 0; eg < 4; ++eg)
#pragma unroll
    for (int r = 0; r < 4; ++r)
        part[wv][kg * 4 + r][eg * 16 + tr] = acc[eg][r];
    __syncthreads();

    // ---- 4-way K-reduce + softmax/top-2 (wave wv: tokens wv*4..wv*4+3) ----
    const int e = l;
    const float be = b[e];
    for (int ti = 0; ti < 4; ++ti) {
        const int t = wv * 4 + ti;
        float logit = part[0][t][e] + part[1][t][e]
                    + part[2][t][e] + part[3][t][e] + be;

        float v1, v2, v3; int i1, i2;
        for (int pass = 0; pass < 2; ++pass) {
            v1 = logit; i1 = e;
#pragma unroll
            for (int off = 32; off >= 1; off >>= 1) {
                float ov = __shfl_xor(v1, off, 64);
                int   oi = __shfl_xor(i1, off, 64);
                if (ov > v1 || (ov == v1 && oi < i1)) { v1 = ov; i1 = oi; }
            }
            v2 = (e == i1) ? -3.4e38f : logit;
            i2 = (e == i1) ? N_EXP : e;
#pragma unroll
            for (int off = 32; off >= 1; off >>= 1) {
                float ov = __shfl_xor(v2, off, 64);
                int   oi = __shfl_xor(i2, off, 64);
                if (ov > v2 || (ov == v2 && oi < i2)) { v2 = ov; i2 = oi; }
            }
            v3 = (e == i1 || e == i2) ? -3.4e38f : logit;
#pragma unroll
            for (int off = 32; off >= 1; off >>= 1) {
                float ov = __shfl_xor(v3, off, 64);
                v3 = (ov > v3) ? ov : v3;
            }
            if (pass == 1) break;
            const bool risky = (v1 - v2 < DELTA) || (v2 - v3 < DELTA);
            if (!risky) break;
            // exact fp32 recompute of candidate experts (wave-uniform path)
            unsigned long long cm = __ballot(logit >= v2 - DELTA2);
            const float* xr = x + (size_t)(t0 + t) * C_IN;
            while (cm) {
                const int ce = __ffsll((unsigned long long)cm) - 1;
                cm &= cm - 1;
                const float* wr = Wf + (size_t)ce * C_IN;
                float p = 0.f;
#pragma unroll 8
                for (int i = 0; i < 32; ++i)
                    p = fmaf(xr[l + 64 * i], wr[l + 64 * i], p);
#pragma unroll
                for (int off = 32; off >= 1; off >>= 1)
                    p += __shfl_xor(p, off, 64);
                if (e == ce) logit = p + be;
            }
        }

        float ex = expf(logit - v1);
        float ssum = ex;
#pragma unroll
        for (int off = 32; off >= 1; off >>= 1)
            ssum += __shfl_xor(ssum, off, 64);
        const float inv = 1.0f / ssum;
        const float p1 = inv;
        const float p2 = expf(v2 - v1) * inv;
        const float o = (e == i1) ? p1 : ((e == i2) ? p2 : 0.0f);
        out[(size_t)(t0 + t) * N_EXP + e] = o;
    }
}

extern "C" void kernel_launch(void* const* d_in, const int* in_sizes, int n_in,
                              void* d_out, int out_size, void* d_ws, size_t ws_size,
                              hipStream_t stream) {
    const float* x = (const float*)d_in[0];   // [4,4096,2048]
    const float* W = (const float*)d_in[1];   // [64,2048]
    const float* b = (const float*)d_in[2];   // [64]
    float* out = (float*)d_out;               // [4,4096,64]

    ushort* whf = (ushort*)d_ws;              // frag-major bf16 hi, 256 KB
    ushort* wlf = whf + N_EXP * C_IN;         // frag-major bf16 lo, 256 KB

    conv_w_kernel<<<512, 256, 0, stream>>>(W, whf, wlf);

    const int tokens = in_sizes[0] / C_IN;    // 16384
    const int grid = tokens / TPB;            // 1024
    topk_gate_kernel<<<grid, 256, 0, stream>>>(x, W, b, whf, wlf, out);
}